// Round 5
// baseline (72.938 us; speedup 1.0000x reference)
//
#include <hip/hip_runtime.h>
#include <math.h>

// RBF layer: out[n,m] = exp(-0.5 * ||x_n - c_m||^2 * exp(-2*ls_m))
// ||x-c||^2 = ||x||^2 + ||c||^2 - 2*x.c ; x.c via bf16 MFMA (A.B^T, K-contig).
// d^2 ~ 512 +- 45; output underflows to 0.0f unless d^2 < ~210 (6.7-sigma tail)
// => bf16 dot error O(0.5) and fp32-vs-bf16 norm mismatch O(1) are invisible.
//
// ROUND 5 = MEASUREMENT ROUND: identical kernels to Round 4, but rbf_mfma is
// launched 3x (idempotent). dur_R5 - dur_R4 = 2*T(rbf_mfma), resolving whether
// the kernel chain is ~5us (harness floor reached) or ~20us (real headroom).
#define K_FEAT 256
#define M_OUT  1024
#define N_ROWS 1024

#define TM 32
#define TN 32
#define LSTR 264  // bf16 row stride: 528B (16B-aligned); 132 floats = 4 mod 32 banks -> 2-way (free) on MFMA reads

typedef short bf16x8 __attribute__((ext_vector_type(8)));
typedef float f32x4  __attribute__((ext_vector_type(4)));

// ---- Pre-kernel: norms[0..1023]=||x_row||^2, norms[1024..2047]=||c_row||^2 ----
__global__ __launch_bounds__(256) void row_norms(
    const float* __restrict__ x, const float* __restrict__ c,
    float* __restrict__ norms)
{
    const int lane = threadIdx.x & 63;
    const int wave = threadIdx.x >> 6;
    const int row  = blockIdx.x * 4 + wave;                  // 0..2047
    const float* src = (row < N_ROWS) ? (x + (size_t)row * K_FEAT)
                                      : (c + (size_t)(row - N_ROWS) * K_FEAT);
    const float4 v = ((const float4*)src)[lane];             // 64 lanes * 4 floats = 256
    float s = v.x * v.x + v.y * v.y + v.z * v.z + v.w * v.w;
    #pragma unroll
    for (int off = 32; off; off >>= 1) s += __shfl_down(s, off, 64);
    if (lane == 0) norms[row] = s;
}

// ---- Main kernel: 32x32 output tile, 4 waves = 2x2 grid of 16x16 MFMA tiles ----
__global__ __launch_bounds__(256, 4) void rbf_mfma(
    const float* __restrict__ x,
    const float* __restrict__ centres,
    const float* __restrict__ log_sigmas,
    const float* __restrict__ norms,
    float* __restrict__ out)
{
    __shared__ unsigned short xs[TM * LSTR];   // 16.9 KB
    __shared__ unsigned short cs[TN * LSTR];   // 16.9 KB  -> 33.8 KB: 4 blocks/CU

    const int tid  = threadIdx.x;
    const int lane = tid & 63;
    const int wave = tid >> 6;
    const int row_base = blockIdx.y * TM;
    const int col_base = blockIdx.x * TN;

    // Stage x (32x256) + c (32x256) as bf16. 2048 8-float chunks, 8/thread.
    #pragma unroll
    for (int l = 0; l < 8; ++l) {
        const int  li    = l & 3;
        const int  chunk = tid + li * 256;     // 0..1023
        const int  row   = chunk >> 5;         // 0..31
        const int  k0    = (chunk & 31) * 8;   // 0..248
        const float* src = (l < 4)
            ? (x       + (size_t)(row_base + row) * K_FEAT + k0)
            : (centres + (size_t)(col_base + row) * K_FEAT + k0);
        const float4 v0 = ((const float4*)src)[0];
        const float4 v1 = ((const float4*)src)[1];
        uint4 p;
        p.x = (__float_as_uint(v0.x) >> 16) | (__float_as_uint(v0.y) & 0xffff0000u);
        p.y = (__float_as_uint(v0.z) >> 16) | (__float_as_uint(v0.w) & 0xffff0000u);
        p.z = (__float_as_uint(v1.x) >> 16) | (__float_as_uint(v1.y) & 0xffff0000u);
        p.w = (__float_as_uint(v1.z) >> 16) | (__float_as_uint(v1.w) & 0xffff0000u);
        unsigned short* dst = (l < 4) ? &xs[row * LSTR + k0] : &cs[row * LSTR + k0];
        *(uint4*)dst = p;
    }
    __syncthreads();

    // MFMA: wave -> (tr,tc) 16x16 tile; K=256 in 8 steps of 32.
    const int m    = lane & 15;
    const int quad = lane >> 4;
    const int tr   = (wave & 1) * 16;
    const int tc   = (wave >> 1) * 16;
    f32x4 acc = {0.f, 0.f, 0.f, 0.f};
    const unsigned short* ap = &xs[(tr + m) * LSTR + quad * 8];
    const unsigned short* bp = &cs[(tc + m) * LSTR + quad * 8];
    #pragma unroll
    for (int kk = 0; kk < 8; ++kk) {
        const bf16x8 a = *(const bf16x8*)(ap + kk * 32);
        const bf16x8 b = *(const bf16x8*)(bp + kk * 32);
        acc = __builtin_amdgcn_mfma_f32_16x16x32_bf16(a, b, acc, 0, 0, 0);
    }

    // Epilogue (no barrier needed): C/D layout col=lane&15, row=quad*4+reg.
    const int   col = col_base + tc + m;
    const float i2s = __expf(-2.0f * log_sigmas[col]);
    const float ncv = norms[N_ROWS + col];
    #pragma unroll
    for (int i = 0; i < 4; ++i) {
        const int   r   = tr + quad * 4 + i;
        const float nxv = norms[row_base + r];
        const float d2  = nxv + ncv - 2.0f * acc[i];
        out[(size_t)(row_base + r) * M_OUT + col] = __expf(-0.5f * d2 * i2s);
    }
}

extern "C" void kernel_launch(void* const* d_in, const int* in_sizes, int n_in,
                              void* d_out, int out_size, void* d_ws, size_t ws_size,
                              hipStream_t stream) {
    const float* x  = (const float*)d_in[0];
    const float* c  = (const float*)d_in[1];
    const float* ls = (const float*)d_in[2];
    float* out   = (float*)d_out;
    float* norms = (float*)d_ws;   // 2048 floats; rewritten every call (ws is re-poisoned)

    row_norms<<<dim3(2 * N_ROWS / 4), dim3(256), 0, stream>>>(x, c, norms);
    dim3 grid(M_OUT / TN, N_ROWS / TM);   // 32 x 32 = 1024 blocks -> 4 blocks/CU
    // Launched 3x deliberately (idempotent): dur delta / 2 = per-launch time.
    rbf_mfma<<<grid, dim3(256), 0, stream>>>(x, c, ls, norms, out);
    rbf_mfma<<<grid, dim3(256), 0, stream>>>(x, c, ls, norms, out);
    rbf_mfma<<<grid, dim3(256), 0, stream>>>(x, c, ls, norms, out);
}

// Round 6
// 62.466 us; speedup vs baseline: 1.1677x; 1.1677x over previous
//
#include <hip/hip_runtime.h>
#include <math.h>

// RBF layer: out[n,m] = exp(-0.5 * ||x_n - c_m||^2 * exp(-2*ls_m))
// ||x-c||^2 = ||x||^2 + ||c||^2 - 2*x.c ; x.c via bf16 MFMA (A.B^T, K-contig).
// d^2 ~ 512 +- 45; output underflows to 0.0f unless d^2 < ~210 (6.7-sigma tail)
// => bf16 dot error O(0.5) and fp32-vs-bf16 norm mismatch O(1) are invisible.
//
// R6: prep kernel converts x,c -> bf16 in ws once (kills 64 MB of redundant
// fp32 L2 staging reads + per-block convert VALU), precomputes 0.5*norms and
// exp(-2*ls). Main kernel: TM=64 x TN=32 tiles, bf16 staging (24 MB total).
#define K_FEAT 256
#define M_OUT  1024
#define N_ROWS 1024

#define TM 64
#define TN 32
#define LSTR 264  // bf16 LDS row stride: 528B (16B-aligned), 132 dwords = 4 mod 32 banks

typedef short bf16x8 __attribute__((ext_vector_type(8)));
typedef float f32x4  __attribute__((ext_vector_type(4)));

// ws layout: [0, 512K)   xb: 1024x256 bf16
//            [512K, 1M)  cb: 1024x256 bf16
//            [1M, ...)   hnx[1024], hnc[1024], sc[1024]  (fp32)
#define WS_CB_OFF   (N_ROWS * K_FEAT)          // in ushorts
#define WS_F32_OFF  (2 * N_ROWS * K_FEAT * 2)  // in bytes

// ---- Prep: bf16 copies + 0.5*row-norms + exp(-2*ls). One wave per row. ----
__global__ __launch_bounds__(256) void prep(
    const float* __restrict__ x, const float* __restrict__ c,
    const float* __restrict__ ls, void* __restrict__ ws)
{
    const int lane = threadIdx.x & 63;
    const int wave = threadIdx.x >> 6;
    const int row  = blockIdx.x * 4 + wave;                  // 0..2047
    unsigned short* bf = (unsigned short*)ws;
    float* hnx = (float*)((char*)ws + WS_F32_OFF);
    float* hnc = hnx + N_ROWS;
    float* sc  = hnc + M_OUT;

    const bool is_x = row < N_ROWS;
    const float* src = is_x ? (x + (size_t)row * K_FEAT)
                            : (c + (size_t)(row - N_ROWS) * K_FEAT);
    const float4 v = ((const float4*)src)[lane];             // 64 lanes * 16B = 1KB/row
    uint2 p;
    p.x = (__float_as_uint(v.x) >> 16) | (__float_as_uint(v.y) & 0xffff0000u);
    p.y = (__float_as_uint(v.z) >> 16) | (__float_as_uint(v.w) & 0xffff0000u);
    unsigned short* dst = bf + (is_x ? (size_t)row * K_FEAT
                                     : (size_t)WS_CB_OFF + (size_t)(row - N_ROWS) * K_FEAT);
    *(uint2*)(dst + lane * 4) = p;

    float s = v.x * v.x + v.y * v.y + v.z * v.z + v.w * v.w;
    #pragma unroll
    for (int off = 32; off; off >>= 1) s += __shfl_down(s, off, 64);
    if (lane == 0) {
        if (is_x) hnx[row] = 0.5f * s;
        else {
            const int m = row - N_ROWS;
            hnc[m] = 0.5f * s;
            sc[m]  = __expf(-2.0f * ls[m]);
        }
    }
}

// ---- Main: 64x32 tile; wave w = 16 rows x 32 cols (two 16x16 MFMA tiles) ----
__global__ __launch_bounds__(256, 2) void rbf_mfma(
    const void* __restrict__ ws, float* __restrict__ out)
{
    __shared__ unsigned short xs[TM * LSTR];   // 33.8 KB
    __shared__ unsigned short cs[TN * LSTR];   // 16.9 KB  -> 50.7 KB: 3 blocks/CU cap

    const unsigned short* xb = (const unsigned short*)ws;
    const unsigned short* cb = xb + WS_CB_OFF;
    const float* hnx = (const float*)((const char*)ws + WS_F32_OFF);
    const float* hnc = hnx + N_ROWS;
    const float* sc  = hnc + M_OUT;

    const int tid  = threadIdx.x;
    const int lane = tid & 63;
    const int wave = tid >> 6;
    const int row_base = blockIdx.y * TM;
    const int col_base = blockIdx.x * TN;

    // Stage 96 bf16 rows (64 x-rows + 32 c-rows) of 512B each: 12 x 16B/thread.
    #pragma unroll
    for (int l = 0; l < 12; ++l) {
        const int chunk = tid + l * 256;       // 0..3071
        const int row   = chunk >> 5;          // 0..95 (uniform block per l)
        const int k0    = (chunk & 31) * 8;    // bf16 elem offset, 16B units
        const unsigned short* src = (l < 8)
            ? (xb + (size_t)(row_base + row) * K_FEAT + k0)
            : (cb + (size_t)(col_base + row - TM) * K_FEAT + k0);
        unsigned short* dst = (l < 8) ? &xs[row * LSTR + k0]
                                      : &cs[(row - TM) * LSTR + k0];
        *(uint4*)dst = *(const uint4*)src;
    }
    __syncthreads();

    // Wave w: rows [w*16, w*16+16), cols [0,32). K=256 in 8 steps.
    const int m    = lane & 15;
    const int quad = lane >> 4;
    const int slab = wave * 16;
    f32x4 acc0 = {0.f, 0.f, 0.f, 0.f};
    f32x4 acc1 = {0.f, 0.f, 0.f, 0.f};
    const unsigned short* ap  = &xs[(slab + m) * LSTR + quad * 8];
    const unsigned short* bp0 = &cs[ m       * LSTR + quad * 8];
    const unsigned short* bp1 = &cs[(16 + m) * LSTR + quad * 8];
    #pragma unroll
    for (int kk = 0; kk < 8; ++kk) {
        const bf16x8 a  = *(const bf16x8*)(ap  + kk * 32);
        const bf16x8 b0 = *(const bf16x8*)(bp0 + kk * 32);
        const bf16x8 b1 = *(const bf16x8*)(bp1 + kk * 32);
        acc0 = __builtin_amdgcn_mfma_f32_16x16x32_bf16(a, b0, acc0, 0, 0, 0);
        acc1 = __builtin_amdgcn_mfma_f32_16x16x32_bf16(a, b1, acc1, 0, 0, 0);
    }

    // Epilogue: C/D layout col=lane&15, row=quad*4+reg (verified m89/m91).
    // out = exp((dot - 0.5||x||^2 - 0.5||c||^2) * exp(-2ls))
    const int   col0 = col_base + m;
    const int   col1 = col_base + 16 + m;
    const float s0 = sc[col0],  s1 = sc[col1];
    const float h0 = hnc[col0], h1 = hnc[col1];
    #pragma unroll
    for (int i = 0; i < 4; ++i) {
        const int   r   = slab + quad * 4 + i;
        const float hx  = hnx[row_base + r];
        float* o = out + (size_t)(row_base + r) * M_OUT;
        o[col0] = __expf((acc0[i] - hx - h0) * s0);
        o[col1] = __expf((acc1[i] - hx - h1) * s1);
    }
}

extern "C" void kernel_launch(void* const* d_in, const int* in_sizes, int n_in,
                              void* d_out, int out_size, void* d_ws, size_t ws_size,
                              hipStream_t stream) {
    const float* x  = (const float*)d_in[0];
    const float* c  = (const float*)d_in[1];
    const float* ls = (const float*)d_in[2];
    float* out = (float*)d_out;

    prep<<<dim3(2 * N_ROWS / 4), dim3(256), 0, stream>>>(x, c, ls, d_ws);
    dim3 grid(M_OUT / TN, N_ROWS / TM);   // 32 x 16 = 512 blocks -> 2 blocks/CU
    rbf_mfma<<<grid, dim3(256), 0, stream>>>(d_ws, out);
}